// Round 15
// baseline (211.961 us; speedup 1.0000x reference)
//
#include <hip/hip_runtime.h>
#include <stdint.h>
#include <math.h>

#define NHEAD 16
#define HDIM 64
#define BATCH 4
#define SEQ 2048
#define NROWS (BATCH*SEQ)   /* 8192 */
#define LOG2E 1.4426950408889634f

typedef _Float16 f16x8 __attribute__((ext_vector_type(8)));
typedef _Float16 f16x4 __attribute__((ext_vector_type(4)));
typedef __fp16 h16x2 __attribute__((ext_vector_type(2)));
typedef float f32x4 __attribute__((ext_vector_type(4)));
typedef float f32x16 __attribute__((ext_vector_type(16)));
typedef unsigned int u32x4 __attribute__((ext_vector_type(4)));

typedef const __attribute__((address_space(1))) unsigned int* gas_ptr;
typedef __attribute__((address_space(3))) unsigned int* las_ptr;

__device__ __forceinline__ void gload_lds16(const void* g, void* l) {
  __builtin_amdgcn_global_load_lds((gas_ptr)g, (las_ptr)l, 16, 0, 0);
}

__device__ __forceinline__ float exp2_fast(float x) {
  float r; asm("v_exp_f32 %0, %1" : "=v"(r) : "v"(x)); return r;
}

__device__ __forceinline__ float max3f(float a, float b, float c) {
  float r; asm("v_max3_f32 %0, %1, %2, %3" : "=v"(r) : "v"(a), "v"(b), "v"(c)); return r;
}

__device__ __forceinline__ unsigned pku(float a, float b) {
  h16x2 p = __builtin_amdgcn_cvt_pkrtz(a, b);
  return __builtin_bit_cast(unsigned, p);
}

// cross-half (lane l <-> l+32) reduce via permlane32_swap: pure VALU, no DS.
// Opaque v_mov breaks value-equality so regalloc cannot coalesce a and b into
// one VGPR (same-register permlane32_swap is a plain swap, not a reduce!).
__device__ __forceinline__ float xhalf_max(float a) {
  float b;
  asm volatile("v_mov_b32 %0, %1" : "=v"(b) : "v"(a));
  asm volatile("v_permlane32_swap_b32 %0, %1" : "+v"(a), "+v"(b));
  return fmaxf(a, b);
}
__device__ __forceinline__ float xhalf_add(float a) {
  float b;
  asm volatile("v_mov_b32 %0, %1" : "=v"(b) : "v"(a));
  asm volatile("v_permlane32_swap_b32 %0, %1" : "+v"(a), "+v"(b));
  return a + b;
}

// ---------------- fused prep: fp32->fp16 cvt (x, w_qkv, w_out) + sincos ----
__global__ void prep_kernel(const float* __restrict__ x,
                            const float* __restrict__ wq,
                            const float* __restrict__ wo,
                            unsigned short* __restrict__ xb,
                            unsigned short* __restrict__ wqb,
                            unsigned short* __restrict__ wob,
                            float2* __restrict__ tab) {
  const int idx = blockIdx.x * blockDim.x + threadIdx.x;
  const int stride = gridDim.x * blockDim.x;
  const int NS = SEQ * 32;                     // 65536 sincos entries
  const int N1 = NROWS * 1024 / 4;             // x float4s
  const int N2 = 3072 * 1024 / 4;              // w_qkv float4s
  const int N3 = 1024 * 1024 / 4;              // w_out float4s

  if (idx < NS) {
    int s = idx >> 5, j = idx & 31;
    float theta = powf(10000.0f, (float)j / 32.0f);
    float ang = (float)s / theta;
    tab[idx] = make_float2(sinf(ang), cosf(ang));
  }
  for (int i = idx; i < N1 + N2 + N3; i += stride) {
    const float* src; unsigned short* dst; int k;
    if (i < N1)            { src = x;  dst = xb;  k = i; }
    else if (i < N1 + N2)  { src = wq; dst = wqb; k = i - N1; }
    else                   { src = wo; dst = wob; k = i - N1 - N2; }
    float4 v = ((const float4*)src)[k];
    f16x4 h;
    h[0] = (_Float16)v.x; h[1] = (_Float16)v.y;
    h[2] = (_Float16)v.z; h[3] = (_Float16)v.w;
    ((f16x4*)dst)[k] = h;
  }
}

// ---------------- QKV GEMM (fp16, BK=64, T2 swizzle) + fused RoPE scatter --
__global__ __launch_bounds__(256)
void gemm_qkv_f16(const unsigned short* __restrict__ A,
                  const unsigned short* __restrict__ B,
                  const float2* __restrict__ tab,
                  unsigned short* __restrict__ Qh,
                  unsigned short* __restrict__ Kh,
                  unsigned short* __restrict__ Vt) {
  const int K = 1024, nk = K >> 6;            // 16 K-tiles of 64
  __shared__ unsigned short sA[2][128 * 64];  // [row][64 elems], chunk-swizzled
  __shared__ unsigned short sB[2][128 * 64];
  const int tid = threadIdx.x;
  const int lane = tid & 63;
  const int wave = tid >> 6;
  const int wr = wave >> 1, wc = wave & 1;
  const long m0 = (long)blockIdx.x * 128;
  const long n0 = (long)blockIdx.y * 128;

  f32x4 acc[4][4] = {};

  auto stage = [&](int buf, int kt) {
    const long k0 = (long)kt * 64;
    const char* Ab = (const char*)A;
    const char* Bb = (const char*)B;
#pragma unroll
    for (int qd = 0; qd < 4; ++qd) {
      int o = qd * 4096 + tid * 16;            // byte off in 16KB tile
      int row = o >> 7;                        // 128B per row
      int colb = (((o >> 4) & 7) ^ (row & 7)) << 4;   // pre-swizzled source chunk
      gload_lds16(Ab + ((m0 + row) * K + k0) * 2 + colb, (char*)&sA[buf][0] + o);
      gload_lds16(Bb + ((n0 + row) * K + k0) * 2 + colb, (char*)&sB[buf][0] + o);
    }
  };

  const int lhi = lane >> 4, llo = lane & 15;
  const int rA = wr * 64 + llo;
  const int rB = wc * 64 + llo;
  int chsw[2];
#pragma unroll
  for (int s = 0; s < 2; ++s) chsw[s] = (((s * 4 + lhi) ^ (llo & 7)) << 3);

  stage(0, 0);
  __syncthreads();
  int cur = 0;

  for (int kt = 0; kt < nk; ++kt) {
    if (kt + 1 < nk) stage(cur ^ 1, kt + 1);
    f16x8 af[2][4], bfr[2][4];
#pragma unroll
    for (int s = 0; s < 2; ++s)
#pragma unroll
      for (int m = 0; m < 4; ++m)
        af[s][m] = *(const f16x8*)&sA[cur][(rA + m * 16) * 64 + chsw[s]];
#pragma unroll
    for (int s = 0; s < 2; ++s)
#pragma unroll
      for (int n = 0; n < 4; ++n)
        bfr[s][n] = *(const f16x8*)&sB[cur][(rB + n * 16) * 64 + chsw[s]];
#pragma unroll
    for (int m = 0; m < 4; ++m)
#pragma unroll
      for (int n = 0; n < 4; ++n) {
        acc[m][n] = __builtin_amdgcn_mfma_f32_16x16x32_f16(af[0][m], bfr[0][n], acc[m][n], 0, 0, 0);
        acc[m][n] = __builtin_amdgcn_mfma_f32_16x16x32_f16(af[1][m], bfr[1][n], acc[m][n], 0, 0, 0);
      }
    __syncthreads();
    cur ^= 1;
  }

  // epilogue: fused RoPE + scatter, per-n hoisted address math
  const int rb0 = (int)m0 + wr * 64 + lhi * 4;
  const int bidx = rb0 >> 11;          // batch, constant per block
  const int s0 = rb0 & 2047;
#pragma unroll
  for (int n = 0; n < 4; ++n) {
    const int col = (int)n0 + wc * 64 + llo + n * 16;
    const int h = col / 192;
    const int off = col - h * 192;
    const int part = off >> 6;
    const int d = off & 63;
    const long bh_ = (long)(bidx * 16 + h);
    if (part < 2) {
      _Float16* dst = (_Float16*)(part == 0 ? Qh : Kh) + bh_ * SEQ * 64 + d;
      const float qs = (part == 0) ? LOG2E : 1.0f;
      const float2* tp = tab + (d >> 1);
      const int sgn = d & 1;
#pragma unroll
      for (int m = 0; m < 4; ++m)
#pragma unroll
        for (int r = 0; r < 4; ++r) {
          int s = s0 + m * 16 + r;
          float v = acc[m][n][r];
          float p = __shfl_xor(v, 1, 64);    // partner (col^1), same part
          float2 sc = tp[s * 32];
          float rot = sgn ? (v * sc.y + p * sc.x) : (v * sc.y - p * sc.x);
          dst[(long)s * 64] = (_Float16)(rot * qs);
        }
    } else {
      _Float16* dst = (_Float16*)Vt + (bh_ * 64 + d) * SEQ;
#pragma unroll
      for (int m = 0; m < 4; ++m)
#pragma unroll
        for (int r = 0; r < 4; ++r)
          dst[s0 + m * 16 + r] = (_Float16)acc[m][n][r];
    }
  }
}

// ---------------- flash attention: 8 waves, 2 tiles/barrier, batched QK ----
// 512 thr = 8 waves x 32 q-rows; 4-buffer LDS (64KB), 2 blocks/CU.
// Per window: QK(t0); QK(t1) issued back-to-back, then SMPV(t0); SMPV(t1) --
// decouples QK(t+1) from PV(t) so SM's VALU chain overlaps other waves' MFMA.
__global__ __launch_bounds__(512, 4)
void attn_kernel(const unsigned short* __restrict__ Qh,
                 const unsigned short* __restrict__ Kh,
                 const unsigned short* __restrict__ Vt,
                 unsigned short* __restrict__ AOut) {
  __shared__ unsigned short sK[4][64 * 64];   // [key][dim], chunk-swizzled
  __shared__ unsigned short sV[4][64 * 64];   // [dim][key], chunk-swizzled

  const int NT = SEQ / 64;                    // 32 tiles
  const int tid = threadIdx.x;
  const int w = tid >> 6, lane = tid & 63;
  const int q32 = lane & 31, hi = lane >> 5;

  // XCD co-location: bid%8 fixed per bh-group -> per-XCD K/V = 4MB (L2-fit)
  const int bid = blockIdx.x;
  const int xcd = bid & 7, rest = bid >> 3;   // rest in [0,64)
  const int bh = (rest >> 3) * 8 + xcd;       // bijective, bh%8 == xcd
  const int qt = rest & 7;
  const int b = bh >> 4, h = bh & 15;
  const int q = qt * 256 + w * 32 + q32;

  // Q B-frags: lane holds Q[d = ds*16 + hi*8 + j][col=q]
  f16x8 aq[4];
#pragma unroll
  for (int ds = 0; ds < 4; ++ds)
    aq[ds] = *(const f16x8*)&Qh[((long)bh * SEQ + q) * 64 + ds * 16 + hi * 8];

  f32x16 acc0 = {}, acc1 = {};
  float mrow = -INFINITY, lrow = 0.f;

  // LDS read offsets: row = t*32+q32, chunk c = s*2+hi, swizzle c^(row&7)
  const int r7 = q32 & 7;
  int off[2][4];
#pragma unroll
  for (int t = 0; t < 2; ++t)
#pragma unroll
    for (int s = 0; s < 4; ++s)
      off[t][s] = (t * 32 + q32) * 64 + (((s * 2 + hi) ^ r7) << 3);

  // staging: thread tid stages 16B chunk tid of each tile, source pre-swizzled
  const int cr = tid >> 3, cp = tid & 7, cps = cp ^ (cr & 7);
  const long kSrc0 = ((long)bh * SEQ + cr) * 64 + cps * 8;   // + kt*4096
  const long vSrc0 = ((long)bh * 64 + cr) * SEQ + cps * 8;   // + kt*64

  auto stage = [&](int buf, int kt) {
    gload_lds16(&Kh[kSrc0 + (long)kt * 4096], (char*)&sK[buf][0] + tid * 16);
    gload_lds16(&Vt[vSrc0 + (long)kt * 64],   (char*)&sV[buf][0] + tid * 16);
  };

#define MKPA(dst, S, R0) {                                        \
    unsigned A0 = pku(S[R0 + 0], S[R0 + 1]);                      \
    unsigned A1 = pku(S[R0 + 2], S[R0 + 3]);                      \
    unsigned B0 = pku(S[R0 + 4], S[R0 + 5]);                      \
    unsigned B1 = pku(S[R0 + 6], S[R0 + 7]);                      \
    asm("v_permlane32_swap_b32 %0, %1" : "+v"(A0), "+v"(B0));     \
    asm("v_permlane32_swap_b32 %0, %1" : "+v"(A1), "+v"(B1));     \
    u32x4 tt; tt[0] = A0; tt[1] = A1; tt[2] = B0; tt[3] = B1;     \
    dst = __builtin_bit_cast(f16x8, tt); }

  // QK(t): scores (log2-domain) into z0/z1, rows=keys, col=q
  auto qk = [&](int t, f32x16& z0, f32x16& z1) {
    const unsigned short* Kb = &sK[t & 3][0];
    f32x16 a = {}, c = {};
    __builtin_amdgcn_s_setprio(1);
#pragma unroll
    for (int ds = 0; ds < 4; ++ds) {
      f16x8 k0 = *(const f16x8*)&Kb[off[0][ds]];
      f16x8 k1 = *(const f16x8*)&Kb[off[1][ds]];
      a = __builtin_amdgcn_mfma_f32_32x32x16_f16(k0, aq[ds], a, 0, 0, 0);
      c = __builtin_amdgcn_mfma_f32_32x32x16_f16(k1, aq[ds], c, 0, 0, 0);
    }
    __builtin_amdgcn_s_setprio(0);
    z0 = a; z1 = c;
  };

  // softmax + PV on precomputed scores for tile t
  auto smpv = [&](int t, f32x16& s0v, f32x16& s1v) {
    // row max over 32 values: max3 tree + permlane cross-half (no DS op)
    float t0 = max3f(s0v[0], s0v[1], s0v[2]);
    float t1 = max3f(s0v[3], s0v[4], s0v[5]);
    float t2 = max3f(s0v[6], s0v[7], s0v[8]);
    float t3 = max3f(s0v[9], s0v[10], s0v[11]);
    float t4 = max3f(s0v[12], s0v[13], s0v[14]);
    float t5 = max3f(s0v[15], s1v[0], s1v[1]);
    float t6 = max3f(s1v[2], s1v[3], s1v[4]);
    float t7 = max3f(s1v[5], s1v[6], s1v[7]);
    float t8 = max3f(s1v[8], s1v[9], s1v[10]);
    float t9 = max3f(s1v[11], s1v[12], s1v[13]);
    float t10 = fmaxf(s1v[14], s1v[15]);
    float u0 = max3f(t0, t1, t2);
    float u1 = max3f(t3, t4, t5);
    float u2 = max3f(t6, t7, t8);
    float u3 = fmaxf(t9, t10);
    float tmax = xhalf_max(fmaxf(max3f(u0, u1, u2), u3));

    if (__any(tmax > mrow + 8.0f)) {          // defer-max (log2 units)
      float mnew = fmaxf(mrow, tmax);
      float al = exp2_fast(mrow - mnew);
      mrow = mnew;
#pragma unroll
      for (int r = 0; r < 16; ++r) { acc0[r] *= al; acc1[r] *= al; }
      lrow *= al;
    }
    const float mr = mrow;

#pragma unroll
    for (int r = 0; r < 16; ++r) {
      s0v[r] = exp2_fast(s0v[r] - mr);
      s1v[r] = exp2_fast(s1v[r] - mr);
    }

    // VALU row-sum (off the PV dependency path -> hides under PV MFMAs)
    float sa[16];
#pragma unroll
    for (int r = 0; r < 16; ++r) sa[r] = s0v[r] + s1v[r];
#pragma unroll
    for (int d = 8; d > 0; d >>= 1)
#pragma unroll
      for (int r = 0; r < d; ++r) sa[r] = sa[r] + sa[r + d];
    lrow += xhalf_add(sa[0]);

    f16x8 pa[4];
    MKPA(pa[0], s0v, 0);
    MKPA(pa[1], s0v, 8);
    MKPA(pa[2], s1v, 0);
    MKPA(pa[3], s1v, 8);

    const unsigned short* Vb = &sV[t & 3][0];
    __builtin_amdgcn_s_setprio(1);
#pragma unroll
    for (int ks = 0; ks < 4; ++ks) {
      f16x8 v0 = *(const f16x8*)&Vb[off[0][ks]];
      f16x8 v1 = *(const f16x8*)&Vb[off[1][ks]];
      acc0 = __builtin_amdgcn_mfma_f32_32x32x16_f16(v0, pa[ks], acc0, 0, 0, 0);
      acc1 = __builtin_amdgcn_mfma_f32_32x32x16_f16(v1, pa[ks], acc1, 0, 0, 0);
    }
    __builtin_amdgcn_s_setprio(0);
  };

  stage(0, 0); stage(1, 1);
  __syncthreads();

  for (int it = 0; it < NT / 2; ++it) {
    const int t0 = it * 2;
    if (it + 1 < NT / 2) { stage((t0 + 2) & 3, t0 + 2); stage((t0 + 3) & 3, t0 + 3); }
    f32x16 x0, x1, y0, y1;
    qk(t0, x0, x1);
    qk(t0 + 1, y0, y1);      // issued before SM(t0): decoupled from PV(t0)
    smpv(t0, x0, x1);
    smpv(t0 + 1, y0, y1);
    __syncthreads();
  }

  // epilogue: out[q][d], d = dt*32 + rg*8 + hi*4 + e
  float inv = 1.f / lrow;
  const long obase = ((long)b * SEQ + q) * 1024 + h * 64;
#define EPI(ACCV, DT)                                              \
  {                                                                \
    _Pragma("unroll")                                              \
    for (int rg = 0; rg < 4; ++rg) {                               \
      f16x4 o;                                                     \
      _Pragma("unroll")                                            \
      for (int e = 0; e < 4; ++e)                                  \
        o[e] = (_Float16)(ACCV[rg * 4 + e] * inv);                 \
      *(f16x4*)&AOut[obase + DT * 32 + rg * 8 + hi * 4] = o;       \
    }                                                              \
  }
  EPI(acc0, 0);
  EPI(acc1, 1);
}

// ---------------- out-proj GEMM (BK=64, T2 swizzle): fp32 out -------------
__global__ __launch_bounds__(256)
void gemm_out_f16(const unsigned short* __restrict__ A,
                  const unsigned short* __restrict__ B,
                  float* __restrict__ C, int M, int N, int K) {
  __shared__ unsigned short sA[2][128 * 64];
  __shared__ unsigned short sB[2][128 * 64];
  const int tid = threadIdx.x;
  const int lane = tid & 63;
  const int wave = tid >> 6;
  const int wr = wave >> 1, wc = wave & 1;
  const long m0 = (long)blockIdx.x * 128;
  const long n0 = (long)blockIdx.y * 128;

  f32x4 acc[4][4] = {};

  auto stage = [&](int buf, int kt) {
    const long k0 = (long)kt * 64;
    const char* Ab = (const char*)A;
    const char* Bb = (const char*)B;
#pragma unroll
    for (int qd = 0; qd < 4; ++qd) {
      int o = qd * 4096 + tid * 16;
      int row = o >> 7;
      int colb = (((o >> 4) & 7) ^ (row & 7)) << 4;
      gload_lds16(Ab + ((m0 + row) * K + k0) * 2 + colb, (char*)&sA[buf][0] + o);
      gload_lds16(Bb + ((n0 + row) * K + k0) * 2 + colb, (char*)&sB[buf][0] + o);
    }
  };

  const int lhi = lane >> 4, llo = lane & 15;
  const int rA = wr * 64 + llo;
  const int rB = wc * 64 + llo;
  int chsw[2];
#pragma unroll
  for (int s = 0; s < 2; ++s) chsw[s] = (((s * 4 + lhi) ^ (llo & 7)) << 3);

  const int nk = K >> 6;
  stage(0, 0);
  __syncthreads();
  int cur = 0;

  for (int kt = 0; kt < nk; ++kt) {
    if (kt + 1 < nk) stage(cur ^ 1, kt + 1);
    f16x8 af[2][4], bfr[2][4];
#pragma unroll
    for (int s = 0; s < 2; ++s)
#pragma unroll
      for (int m = 0; m < 4; ++m)
        af[s][m] = *(const f16x8*)&sA[cur][(rA + m * 16) * 64 + chsw[s]];
#pragma unroll
    for (int s = 0; s < 2; ++s)
#pragma unroll
      for (int n = 0; n < 4; ++n)
        bfr[s][n] = *(const f16x8*)&sB[cur][(rB + n * 16) * 64 + chsw[s]];
#pragma unroll
    for (int m = 0; m < 4; ++m)
#pragma unroll
      for (int n = 0; n < 4; ++n) {
        acc[m][n] = __builtin_amdgcn_mfma_f32_16x16x32_f16(af[0][m], bfr[0][n], acc[m][n], 0, 0, 0);
        acc[m][n] = __builtin_amdgcn_mfma_f32_16x16x32_f16(af[1][m], bfr[1][n], acc[m][n], 0, 0, 0);
      }
    __syncthreads();
    cur ^= 1;
  }

  const long rbase = m0 + wr * 64 + lhi * 4;
#pragma unroll
  for (int n = 0; n < 4; ++n) {
    const long col = n0 + wc * 64 + llo + n * 16;
#pragma unroll
    for (int m = 0; m < 4; ++m)
#pragma unroll
      for (int r = 0; r < 4; ++r)
        C[(rbase + m * 16 + r) * N + col] = acc[m][n][r];
  }
}

// ---------------- launch ----------------
extern "C" void kernel_launch(void* const* d_in, const int* in_sizes, int n_in,
                              void* d_out, int out_size, void* d_ws, size_t ws_size,
                              hipStream_t stream) {
  const float* x     = (const float*)d_in[0];
  const float* w_qkv = (const float*)d_in[1];
  const float* w_out = (const float*)d_in[2];
  float* out = (float*)d_out;
  char* ws = (char*)d_ws;

  unsigned short* xb    = (unsigned short*)(ws + 0);           // 16 MB
  unsigned short* attnb = xb;                                  // alias (x dead)
  unsigned short* wqkvb = (unsigned short*)(ws + 16777216);    //  6 MB
  unsigned short* woutb = (unsigned short*)(ws + 23068672);    //  2 MB
  unsigned short* Qh    = (unsigned short*)(ws + 25165824);    // 16 MB
  unsigned short* Kh    = (unsigned short*)(ws + 41943040);    // 16 MB
  unsigned short* Vt    = (unsigned short*)(ws + 58720256);    // 16 MB
  float2*         tab   = (float2*)(ws + 75497472);            // 512 KB

  prep_kernel<<<2048, 256, 0, stream>>>(x, w_qkv, w_out, xb, wqkvb, woutb, tab);
  gemm_qkv_f16<<<dim3(64, 24), 256, 0, stream>>>(xb, wqkvb, tab, Qh, Kh, Vt);
  attn_kernel<<<512, 512, 0, stream>>>(Qh, Kh, Vt, attnb);
  gemm_out_f16<<<dim3(64, 8), 256, 0, stream>>>(attnb, woutb, out, NROWS, 1024, 1024);
}

// Round 16
// 199.997 us; speedup vs baseline: 1.0598x; 1.0598x over previous
//
#include <hip/hip_runtime.h>
#include <stdint.h>
#include <math.h>

#define NHEAD 16
#define HDIM 64
#define BATCH 4
#define SEQ 2048
#define NROWS (BATCH*SEQ)   /* 8192 */
#define LOG2E 1.4426950408889634f

typedef _Float16 f16x8 __attribute__((ext_vector_type(8)));
typedef _Float16 f16x4 __attribute__((ext_vector_type(4)));
typedef __fp16 h16x2 __attribute__((ext_vector_type(2)));
typedef float f32x4 __attribute__((ext_vector_type(4)));
typedef float f32x16 __attribute__((ext_vector_type(16)));
typedef unsigned int u32x4 __attribute__((ext_vector_type(4)));

typedef const __attribute__((address_space(1))) unsigned int* gas_ptr;
typedef __attribute__((address_space(3))) unsigned int* las_ptr;

__device__ __forceinline__ void gload_lds16(const void* g, void* l) {
  __builtin_amdgcn_global_load_lds((gas_ptr)g, (las_ptr)l, 16, 0, 0);
}

__device__ __forceinline__ float exp2_fast(float x) {
  float r; asm("v_exp_f32 %0, %1" : "=v"(r) : "v"(x)); return r;
}

__device__ __forceinline__ float max3f(float a, float b, float c) {
  float r; asm("v_max3_f32 %0, %1, %2, %3" : "=v"(r) : "v"(a), "v"(b), "v"(c)); return r;
}

__device__ __forceinline__ unsigned pku(float a, float b) {
  h16x2 p = __builtin_amdgcn_cvt_pkrtz(a, b);
  return __builtin_bit_cast(unsigned, p);
}

// cross-half (lane l <-> l+32) reduce via permlane32_swap: pure VALU, no DS.
// Opaque v_mov breaks value-equality so regalloc cannot coalesce a and b into
// one VGPR (same-register permlane32_swap is a plain swap, not a reduce!).
__device__ __forceinline__ float xhalf_max(float a) {
  float b;
  asm volatile("v_mov_b32 %0, %1" : "=v"(b) : "v"(a));
  asm volatile("v_permlane32_swap_b32 %0, %1" : "+v"(a), "+v"(b));
  return fmaxf(a, b);
}
__device__ __forceinline__ float xhalf_add(float a) {
  float b;
  asm volatile("v_mov_b32 %0, %1" : "=v"(b) : "v"(a));
  asm volatile("v_permlane32_swap_b32 %0, %1" : "+v"(a), "+v"(b));
  return a + b;
}

// ---------------- fused prep: fp32->fp16 cvt (x, w_qkv, w_out) + sincos ----
__global__ void prep_kernel(const float* __restrict__ x,
                            const float* __restrict__ wq,
                            const float* __restrict__ wo,
                            unsigned short* __restrict__ xb,
                            unsigned short* __restrict__ wqb,
                            unsigned short* __restrict__ wob,
                            float2* __restrict__ tab) {
  const int idx = blockIdx.x * blockDim.x + threadIdx.x;
  const int stride = gridDim.x * blockDim.x;
  const int NS = SEQ * 32;                     // 65536 sincos entries
  const int N1 = NROWS * 1024 / 4;             // x float4s
  const int N2 = 3072 * 1024 / 4;              // w_qkv float4s
  const int N3 = 1024 * 1024 / 4;              // w_out float4s

  if (idx < NS) {
    int s = idx >> 5, j = idx & 31;
    float theta = powf(10000.0f, (float)j / 32.0f);
    float ang = (float)s / theta;
    tab[idx] = make_float2(sinf(ang), cosf(ang));
  }
  for (int i = idx; i < N1 + N2 + N3; i += stride) {
    const float* src; unsigned short* dst; int k;
    if (i < N1)            { src = x;  dst = xb;  k = i; }
    else if (i < N1 + N2)  { src = wq; dst = wqb; k = i - N1; }
    else                   { src = wo; dst = wob; k = i - N1 - N2; }
    float4 v = ((const float4*)src)[k];
    f16x4 h;
    h[0] = (_Float16)v.x; h[1] = (_Float16)v.y;
    h[2] = (_Float16)v.z; h[3] = (_Float16)v.w;
    ((f16x4*)dst)[k] = h;
  }
}

// ---------------- QKV GEMM (fp16, BK=64, T2 swizzle) + fused RoPE scatter --
__global__ __launch_bounds__(256)
void gemm_qkv_f16(const unsigned short* __restrict__ A,
                  const unsigned short* __restrict__ B,
                  const float2* __restrict__ tab,
                  unsigned short* __restrict__ Qh,
                  unsigned short* __restrict__ Kh,
                  unsigned short* __restrict__ Vt) {
  const int K = 1024, nk = K >> 6;            // 16 K-tiles of 64
  __shared__ unsigned short sA[2][128 * 64];  // [row][64 elems], chunk-swizzled
  __shared__ unsigned short sB[2][128 * 64];
  const int tid = threadIdx.x;
  const int lane = tid & 63;
  const int wave = tid >> 6;
  const int wr = wave >> 1, wc = wave & 1;
  const long m0 = (long)blockIdx.x * 128;
  const long n0 = (long)blockIdx.y * 128;

  f32x4 acc[4][4] = {};

  auto stage = [&](int buf, int kt) {
    const long k0 = (long)kt * 64;
    const char* Ab = (const char*)A;
    const char* Bb = (const char*)B;
#pragma unroll
    for (int qd = 0; qd < 4; ++qd) {
      int o = qd * 4096 + tid * 16;            // byte off in 16KB tile
      int row = o >> 7;                        // 128B per row
      int colb = (((o >> 4) & 7) ^ (row & 7)) << 4;   // pre-swizzled source chunk
      gload_lds16(Ab + ((m0 + row) * K + k0) * 2 + colb, (char*)&sA[buf][0] + o);
      gload_lds16(Bb + ((n0 + row) * K + k0) * 2 + colb, (char*)&sB[buf][0] + o);
    }
  };

  const int lhi = lane >> 4, llo = lane & 15;
  const int rA = wr * 64 + llo;
  const int rB = wc * 64 + llo;
  int chsw[2];
#pragma unroll
  for (int s = 0; s < 2; ++s) chsw[s] = (((s * 4 + lhi) ^ (llo & 7)) << 3);

  stage(0, 0);
  __syncthreads();
  int cur = 0;

  for (int kt = 0; kt < nk; ++kt) {
    if (kt + 1 < nk) stage(cur ^ 1, kt + 1);
    f16x8 af[2][4], bfr[2][4];
#pragma unroll
    for (int s = 0; s < 2; ++s)
#pragma unroll
      for (int m = 0; m < 4; ++m)
        af[s][m] = *(const f16x8*)&sA[cur][(rA + m * 16) * 64 + chsw[s]];
#pragma unroll
    for (int s = 0; s < 2; ++s)
#pragma unroll
      for (int n = 0; n < 4; ++n)
        bfr[s][n] = *(const f16x8*)&sB[cur][(rB + n * 16) * 64 + chsw[s]];
#pragma unroll
    for (int m = 0; m < 4; ++m)
#pragma unroll
      for (int n = 0; n < 4; ++n) {
        acc[m][n] = __builtin_amdgcn_mfma_f32_16x16x32_f16(af[0][m], bfr[0][n], acc[m][n], 0, 0, 0);
        acc[m][n] = __builtin_amdgcn_mfma_f32_16x16x32_f16(af[1][m], bfr[1][n], acc[m][n], 0, 0, 0);
      }
    __syncthreads();
    cur ^= 1;
  }

  // epilogue: fused RoPE + scatter, per-n hoisted address math
  const int rb0 = (int)m0 + wr * 64 + lhi * 4;
  const int bidx = rb0 >> 11;          // batch, constant per block
  const int s0 = rb0 & 2047;
#pragma unroll
  for (int n = 0; n < 4; ++n) {
    const int col = (int)n0 + wc * 64 + llo + n * 16;
    const int h = col / 192;
    const int off = col - h * 192;
    const int part = off >> 6;
    const int d = off & 63;
    const long bh_ = (long)(bidx * 16 + h);
    if (part < 2) {
      _Float16* dst = (_Float16*)(part == 0 ? Qh : Kh) + bh_ * SEQ * 64 + d;
      const float qs = (part == 0) ? LOG2E : 1.0f;
      const float2* tp = tab + (d >> 1);
      const int sgn = d & 1;
#pragma unroll
      for (int m = 0; m < 4; ++m)
#pragma unroll
        for (int r = 0; r < 4; ++r) {
          int s = s0 + m * 16 + r;
          float v = acc[m][n][r];
          float p = __shfl_xor(v, 1, 64);    // partner (col^1), same part
          float2 sc = tp[s * 32];
          float rot = sgn ? (v * sc.y + p * sc.x) : (v * sc.y - p * sc.x);
          dst[(long)s * 64] = (_Float16)(rot * qs);
        }
    } else {
      _Float16* dst = (_Float16*)Vt + (bh_ * 64 + d) * SEQ;
#pragma unroll
      for (int m = 0; m < 4; ++m)
#pragma unroll
        for (int r = 0; r < 4; ++r)
          dst[s0 + m * 16 + r] = (_Float16)acc[m][n][r];
    }
  }
}

// ---------------- flash attention: 8 waves, 2 tiles/barrier, XCD-coloc -----
// 512 thr = 8 waves x 32 q-rows; 4-buffer LDS (64KB), 2 blocks/CU.
// R14 structure (serial tile: QK->SM->PV, one score set, no spills);
// row-sum on VALU (off PV dep path) + permlane cross-half reduces.
__global__ __launch_bounds__(512, 4)
void attn_kernel(const unsigned short* __restrict__ Qh,
                 const unsigned short* __restrict__ Kh,
                 const unsigned short* __restrict__ Vt,
                 unsigned short* __restrict__ AOut) {
  __shared__ unsigned short sK[4][64 * 64];   // [key][dim], chunk-swizzled
  __shared__ unsigned short sV[4][64 * 64];   // [dim][key], chunk-swizzled

  const int NT = SEQ / 64;                    // 32 tiles
  const int tid = threadIdx.x;
  const int w = tid >> 6, lane = tid & 63;
  const int q32 = lane & 31, hi = lane >> 5;

  // XCD co-location: bid%8 fixed per bh-group -> per-XCD K/V = 4MB (L2-fit)
  const int bid = blockIdx.x;
  const int xcd = bid & 7, rest = bid >> 3;   // rest in [0,64)
  const int bh = (rest >> 3) * 8 + xcd;       // bijective, bh%8 == xcd
  const int qt = rest & 7;
  const int b = bh >> 4, h = bh & 15;
  const int q = qt * 256 + w * 32 + q32;

  // Q B-frags: lane holds Q[d = ds*16 + hi*8 + j][col=q]
  f16x8 aq[4];
#pragma unroll
  for (int ds = 0; ds < 4; ++ds)
    aq[ds] = *(const f16x8*)&Qh[((long)bh * SEQ + q) * 64 + ds * 16 + hi * 8];

  f32x16 acc0 = {}, acc1 = {};
  float mrow = -INFINITY, lrow = 0.f;

  // LDS read offsets: row = t*32+q32, chunk c = s*2+hi, swizzle c^(row&7)
  const int r7 = q32 & 7;
  int off[2][4];
#pragma unroll
  for (int t = 0; t < 2; ++t)
#pragma unroll
    for (int s = 0; s < 4; ++s)
      off[t][s] = (t * 32 + q32) * 64 + (((s * 2 + hi) ^ r7) << 3);

  // staging: thread tid stages 16B chunk tid of each tile, source pre-swizzled
  const int cr = tid >> 3, cp = tid & 7, cps = cp ^ (cr & 7);
  const long kSrc0 = ((long)bh * SEQ + cr) * 64 + cps * 8;   // + kt*4096
  const long vSrc0 = ((long)bh * 64 + cr) * SEQ + cps * 8;   // + kt*64

  auto stage = [&](int buf, int kt) {
    gload_lds16(&Kh[kSrc0 + (long)kt * 4096], (char*)&sK[buf][0] + tid * 16);
    gload_lds16(&Vt[vSrc0 + (long)kt * 64],   (char*)&sV[buf][0] + tid * 16);
  };

#define MKPA(dst, S, R0) {                                        \
    unsigned A0 = pku(S[R0 + 0], S[R0 + 1]);                      \
    unsigned A1 = pku(S[R0 + 2], S[R0 + 3]);                      \
    unsigned B0 = pku(S[R0 + 4], S[R0 + 5]);                      \
    unsigned B1 = pku(S[R0 + 6], S[R0 + 7]);                      \
    asm("v_permlane32_swap_b32 %0, %1" : "+v"(A0), "+v"(B0));     \
    asm("v_permlane32_swap_b32 %0, %1" : "+v"(A1), "+v"(B1));     \
    u32x4 tt; tt[0] = A0; tt[1] = A1; tt[2] = B0; tt[3] = B1;     \
    dst = __builtin_bit_cast(f16x8, tt); }

  // one full tile: QK -> softmax -> PV, all from bufs[t&3]
  auto tile = [&](int t) {
    const unsigned short* Kb = &sK[t & 3][0];
    const unsigned short* Vb = &sV[t & 3][0];

    f32x16 s0v = {}, s1v = {};
    __builtin_amdgcn_s_setprio(1);
#pragma unroll
    for (int ds = 0; ds < 4; ++ds) {
      f16x8 k0 = *(const f16x8*)&Kb[off[0][ds]];
      f16x8 k1 = *(const f16x8*)&Kb[off[1][ds]];
      s0v = __builtin_amdgcn_mfma_f32_32x32x16_f16(k0, aq[ds], s0v, 0, 0, 0);
      s1v = __builtin_amdgcn_mfma_f32_32x32x16_f16(k1, aq[ds], s1v, 0, 0, 0);
    }
    __builtin_amdgcn_s_setprio(0);

    // row max over 32 values: max3 tree + permlane cross-half (no DS op)
    float t0 = max3f(s0v[0], s0v[1], s0v[2]);
    float t1 = max3f(s0v[3], s0v[4], s0v[5]);
    float t2 = max3f(s0v[6], s0v[7], s0v[8]);
    float t3 = max3f(s0v[9], s0v[10], s0v[11]);
    float t4 = max3f(s0v[12], s0v[13], s0v[14]);
    float t5 = max3f(s0v[15], s1v[0], s1v[1]);
    float t6 = max3f(s1v[2], s1v[3], s1v[4]);
    float t7 = max3f(s1v[5], s1v[6], s1v[7]);
    float t8 = max3f(s1v[8], s1v[9], s1v[10]);
    float t9 = max3f(s1v[11], s1v[12], s1v[13]);
    float t10 = fmaxf(s1v[14], s1v[15]);
    float u0 = max3f(t0, t1, t2);
    float u1 = max3f(t3, t4, t5);
    float u2 = max3f(t6, t7, t8);
    float u3 = fmaxf(t9, t10);
    float tmax = xhalf_max(fmaxf(max3f(u0, u1, u2), u3));

    if (__any(tmax > mrow + 8.0f)) {          // defer-max (log2 units)
      float mnew = fmaxf(mrow, tmax);
      float al = exp2_fast(mrow - mnew);
      mrow = mnew;
#pragma unroll
      for (int r = 0; r < 16; ++r) { acc0[r] *= al; acc1[r] *= al; }
      lrow *= al;
    }
    const float mr = mrow;

#pragma unroll
    for (int r = 0; r < 16; ++r) {
      s0v[r] = exp2_fast(s0v[r] - mr);
      s1v[r] = exp2_fast(s1v[r] - mr);
    }

    // VALU row-sum (off the PV dependency path -> hides under PV MFMAs)
    float sa[16];
#pragma unroll
    for (int r = 0; r < 16; ++r) sa[r] = s0v[r] + s1v[r];
#pragma unroll
    for (int d = 8; d > 0; d >>= 1)
#pragma unroll
      for (int r = 0; r < d; ++r) sa[r] = sa[r] + sa[r + d];
    lrow += xhalf_add(sa[0]);

    f16x8 pa[4];
    MKPA(pa[0], s0v, 0);
    MKPA(pa[1], s0v, 8);
    MKPA(pa[2], s1v, 0);
    MKPA(pa[3], s1v, 8);

    const unsigned short* Vb2 = Vb;
    __builtin_amdgcn_s_setprio(1);
#pragma unroll
    for (int ks = 0; ks < 4; ++ks) {
      f16x8 v0 = *(const f16x8*)&Vb2[off[0][ks]];
      f16x8 v1 = *(const f16x8*)&Vb2[off[1][ks]];
      acc0 = __builtin_amdgcn_mfma_f32_32x32x16_f16(v0, pa[ks], acc0, 0, 0, 0);
      acc1 = __builtin_amdgcn_mfma_f32_32x32x16_f16(v1, pa[ks], acc1, 0, 0, 0);
    }
    __builtin_amdgcn_s_setprio(0);
  };

  stage(0, 0); stage(1, 1);
  __syncthreads();

  for (int it = 0; it < NT / 2; ++it) {
    const int t0 = it * 2;
    if (it + 1 < NT / 2) { stage((t0 + 2) & 3, t0 + 2); stage((t0 + 3) & 3, t0 + 3); }
    tile(t0);
    tile(t0 + 1);
    __syncthreads();
  }

  // epilogue: out[q][d], d = dt*32 + rg*8 + hi*4 + e
  float inv = 1.f / lrow;
  const long obase = ((long)b * SEQ + q) * 1024 + h * 64;
#define EPI(ACCV, DT)                                              \
  {                                                                \
    _Pragma("unroll")                                              \
    for (int rg = 0; rg < 4; ++rg) {                               \
      f16x4 o;                                                     \
      _Pragma("unroll")                                            \
      for (int e = 0; e < 4; ++e)                                  \
        o[e] = (_Float16)(ACCV[rg * 4 + e] * inv);                 \
      *(f16x4*)&AOut[obase + DT * 32 + rg * 8 + hi * 4] = o;       \
    }                                                              \
  }
  EPI(acc0, 0);
  EPI(acc1, 1);
}

// ---------------- out-proj GEMM (BK=64, T2 swizzle): fp32 out -------------
__global__ __launch_bounds__(256)
void gemm_out_f16(const unsigned short* __restrict__ A,
                  const unsigned short* __restrict__ B,
                  float* __restrict__ C, int M, int N, int K) {
  __shared__ unsigned short sA[2][128 * 64];
  __shared__ unsigned short sB[2][128 * 64];
  const int tid = threadIdx.x;
  const int lane = tid & 63;
  const int wave = tid >> 6;
  const int wr = wave >> 1, wc = wave & 1;
  const long m0 = (long)blockIdx.x * 128;
  const long n0 = (long)blockIdx.y * 128;

  f32x4 acc[4][4] = {};

  auto stage = [&](int buf, int kt) {
    const long k0 = (long)kt * 64;
    const char* Ab = (const char*)A;
    const char* Bb = (const char*)B;
#pragma unroll
    for (int qd = 0; qd < 4; ++qd) {
      int o = qd * 4096 + tid * 16;
      int row = o >> 7;
      int colb = (((o >> 4) & 7) ^ (row & 7)) << 4;
      gload_lds16(Ab + ((m0 + row) * K + k0) * 2 + colb, (char*)&sA[buf][0] + o);
      gload_lds16(Bb + ((n0 + row) * K + k0) * 2 + colb, (char*)&sB[buf][0] + o);
    }
  };

  const int lhi = lane >> 4, llo = lane & 15;
  const int rA = wr * 64 + llo;
  const int rB = wc * 64 + llo;
  int chsw[2];
#pragma unroll
  for (int s = 0; s < 2; ++s) chsw[s] = (((s * 4 + lhi) ^ (llo & 7)) << 3);

  const int nk = K >> 6;
  stage(0, 0);
  __syncthreads();
  int cur = 0;

  for (int kt = 0; kt < nk; ++kt) {
    if (kt + 1 < nk) stage(cur ^ 1, kt + 1);
    f16x8 af[2][4], bfr[2][4];
#pragma unroll
    for (int s = 0; s < 2; ++s)
#pragma unroll
      for (int m = 0; m < 4; ++m)
        af[s][m] = *(const f16x8*)&sA[cur][(rA + m * 16) * 64 + chsw[s]];
#pragma unroll
    for (int s = 0; s < 2; ++s)
#pragma unroll
      for (int n = 0; n < 4; ++n)
        bfr[s][n] = *(const f16x8*)&sB[cur][(rB + n * 16) * 64 + chsw[s]];
#pragma unroll
    for (int m = 0; m < 4; ++m)
#pragma unroll
      for (int n = 0; n < 4; ++n) {
        acc[m][n] = __builtin_amdgcn_mfma_f32_16x16x32_f16(af[0][m], bfr[0][n], acc[m][n], 0, 0, 0);
        acc[m][n] = __builtin_amdgcn_mfma_f32_16x16x32_f16(af[1][m], bfr[1][n], acc[m][n], 0, 0, 0);
      }
    __syncthreads();
    cur ^= 1;
  }

  const long rbase = m0 + wr * 64 + lhi * 4;
#pragma unroll
  for (int n = 0; n < 4; ++n) {
    const long col = n0 + wc * 64 + llo + n * 16;
#pragma unroll
    for (int m = 0; m < 4; ++m)
#pragma unroll
      for (int r = 0; r < 4; ++r)
        C[(rbase + m * 16 + r) * N + col] = acc[m][n][r];
  }
}

// ---------------- launch ----------------
extern "C" void kernel_launch(void* const* d_in, const int* in_sizes, int n_in,
                              void* d_out, int out_size, void* d_ws, size_t ws_size,
                              hipStream_t stream) {
  const float* x     = (const float*)d_in[0];
  const float* w_qkv = (const float*)d_in[1];
  const float* w_out = (const float*)d_in[2];
  float* out = (float*)d_out;
  char* ws = (char*)d_ws;

  unsigned short* xb    = (unsigned short*)(ws + 0);           // 16 MB
  unsigned short* attnb = xb;                                  // alias (x dead)
  unsigned short* wqkvb = (unsigned short*)(ws + 16777216);    //  6 MB
  unsigned short* woutb = (unsigned short*)(ws + 23068672);    //  2 MB
  unsigned short* Qh    = (unsigned short*)(ws + 25165824);    // 16 MB
  unsigned short* Kh    = (unsigned short*)(ws + 41943040);    // 16 MB
  unsigned short* Vt    = (unsigned short*)(ws + 58720256);    // 16 MB
  float2*         tab   = (float2*)(ws + 75497472);            // 512 KB

  prep_kernel<<<2048, 256, 0, stream>>>(x, w_qkv, w_out, xb, wqkvb, woutb, tab);
  gemm_qkv_f16<<<dim3(64, 24), 256, 0, stream>>>(xb, wqkvb, tab, Qh, Kh, Vt);
  attn_kernel<<<512, 512, 0, stream>>>(Qh, Kh, Vt, attnb);
  gemm_out_f16<<<dim3(64, 8), 256, 0, stream>>>(attnb, woutb, out, NROWS, 1024, 1024);
}